// Round 2
// baseline (211.304 us; speedup 1.0000x reference)
//
#include <hip/hip_runtime.h>
#include <hip/hip_bf16.h>

#define DF 128
#define BSH 5                 // fine bucket = dst >> 5  (32 nodes)
#define BNODES 32
#define NBMAX 2048            // max fine buckets (50000/32 = 1563)
#define CSH 10                // coarse bucket = dst >> 10 (1024 nodes)
#define NC_ 49                // ceil(50000/1024)
#define CAPC 24576            // staging slots per coarse bucket (mean ~16.3k)
#define PCHUNK 4096           // edges per prep edge-block
#define CHUNKB 4096           // edges per binB block
#define KMAX 6                // CAPC / CHUNKB
#define TILE 2048             // edges per agg LDS tile (bucket ~512)
#define ASTRIDE 68            // uints per abuf row (64 data + 4 pad)
#define SRCMASK 0x07ffffffu   // final pairs: src in low 27 bits, dstLocal in 27..31

typedef __attribute__((ext_vector_type(8))) short short8;
typedef __attribute__((ext_vector_type(4))) float floatx4;

__device__ __forceinline__ ushort f2bf(float f) {
    __hip_bfloat16 h = __float2bfloat16(f);   // RNE
    return *reinterpret_cast<ushort*>(&h);
}

// ---------------------------------------------------------------------------
// K1: [0,EB) edge blocks | [EB,EB+WB) weight convert | rest x convert.
// Edge block: fine-hist -> ghist (global atomics), coarse-sort chunk in LDS,
// reserve staging range per coarse bucket (atomic gcurC), write COALESCED
// runs (~83 edges) into stagingC.  Staged pk = src(16) | (dst&1023)<<16 | c<<26.
// Last edge block scans ghist -> gbase/gcurF (fine layout of final pairs).
// ---------------------------------------------------------------------------
__global__ __launch_bounds__(512) void prep_kernel(
    const float* __restrict__ x, ushort* __restrict__ xbf, int n4,
    const float* __restrict__ W1, const float* __restrict__ W2,
    const float* __restrict__ b1, const float* __restrict__ b2,
    ushort* __restrict__ w1bf, ushort* __restrict__ w2bf, float* __restrict__ bias,
    const int* __restrict__ src, const int* __restrict__ dst,
    int* __restrict__ ghist, int* __restrict__ done, int* __restrict__ gcurC,
    uint* __restrict__ stagingC, int* __restrict__ gbase, int* __restrict__ gcurF,
    int n_edges, int EB, int WB, int nb)
{
    __shared__ int  hf[NBMAX];      // 8 KB fine hist / scan scratch
    __shared__ int  hc[NC_];
    __shared__ int  lcur[NC_];
    __shared__ int  wb[NC_];
    __shared__ uint stg[PCHUNK];    // 16 KB
    __shared__ int  isLast;

    int bid = blockIdx.x;
    int tid = threadIdx.x;

    if (bid < EB) {
        int base = bid * PCHUNK;
        int cnt = n_edges - base; if (cnt > PCHUNK) cnt = PCHUNK;

        for (int j = tid; j < nb; j += 512) hf[j] = 0;
        if (tid < NC_) hc[tid] = 0;
        __syncthreads();
#pragma unroll
        for (int k = 0; k < PCHUNK / 512; ++k) {
            int i = k * 512 + tid;
            if (i < cnt) {
                int d = dst[base + i];
                atomicAdd(&hf[d >> BSH], 1);
                atomicAdd(&hc[d >> CSH], 1);
            }
        }
        __syncthreads();
        // merge fine hist to global
        for (int j = tid; j < nb; j += 512) {
            int c = hf[j];
            if (c) atomicAdd(&ghist[j], c);
        }
        // coarse scan (49 entries) + global staging reservation: wave 0
        if (tid < 64) {
            int c = (tid < NC_) ? hc[tid] : 0;
            int s = c;
#pragma unroll
            for (int off = 1; off < 64; off <<= 1) {
                int u = __shfl_up(s, off);
                if (tid >= off) s += u;
            }
            if (tid < NC_) {
                int excl = s - c;
                lcur[tid] = excl;
                int gp = 0;
                if (c > 0) gp = atomicAdd(&gcurC[tid], c);
                wb[tid] = tid * CAPC + gp - excl;
            }
        }
        __syncthreads();
        // local coarse sort into stg
#pragma unroll
        for (int k = 0; k < PCHUNK / 512; ++k) {
            int i = k * 512 + tid;
            if (i < cnt) {
                int e = base + i;
                int d = dst[e];
                int c = d >> CSH;
                uint pk = (uint)src[e] | ((uint)(d & 1023) << 16) | ((uint)c << 26);
                int p = atomicAdd(&lcur[c], 1);
                stg[p] = pk;
            }
        }
        __syncthreads();
        // coalesced write of coarse runs
#pragma unroll
        for (int k = 0; k < PCHUNK / 512; ++k) {
            int i = k * 512 + tid;
            if (i < cnt) {
                uint pk = stg[i];
                int c = (int)(pk >> 26);
                stagingC[wb[c] + i] = pk;
            }
        }
        __threadfence();
        __syncthreads();
        if (tid == 0) isLast = (atomicAdd(done, 1) == EB - 1);
        __syncthreads();
        if (isLast) {
            // exclusive scan of ghist[0..nb): 512 threads x 4
            int b0 = tid * 4;
            int vals[4];
            int s = 0;
#pragma unroll
            for (int k = 0; k < 4; ++k) {
                int idx = b0 + k;
                int v = (idx < nb)
                    ? __hip_atomic_load(&ghist[idx], __ATOMIC_RELAXED,
                                        __HIP_MEMORY_SCOPE_AGENT)
                    : 0;
                vals[k] = v; s += v;
            }
            hf[tid] = s;
            __syncthreads();
            for (int off = 1; off < 512; off <<= 1) {
                int u = (tid >= off) ? hf[tid - off] : 0;
                __syncthreads();
                hf[tid] += u;
                __syncthreads();
            }
            int run = hf[tid] - s;
#pragma unroll
            for (int k = 0; k < 4; ++k) {
                int idx = b0 + k;
                if (idx < nb) { gbase[idx] = run; gcurF[idx] = run; run += vals[k]; }
            }
            if (tid == 0) gbase[nb] = n_edges;
        }
    } else if (bid < EB + WB) {
        int i = (bid - EB) * 512 + tid;
        if (i < DF * DF) {
            w1bf[i] = f2bf(W1[i]);
            w2bf[i] = f2bf(W2[i]);
        }
        if (i < DF) bias[i] = b1[i] + b2[i];
    } else {
        int i = (bid - EB - WB) * 512 + tid;
        if (i < n4) {
            float4 v = reinterpret_cast<const float4*>(x)[i];
            ushort4 o;
            o.x = f2bf(v.x); o.y = f2bf(v.y); o.z = f2bf(v.z); o.w = f2bf(v.w);
            reinterpret_cast<ushort4*>(xbf)[i] = o;
        }
    }
}

// ---------------------------------------------------------------------------
// K2: fine binning within one coarse chunk. Block (c, k) sorts 4096 staged
// edges of coarse bucket c by fine-local (32 bins), reserves per-fine ranges
// (atomic gcurF), writes COALESCED runs (~128 edges) into final pairs with
// pk = src | dstLocal<<27. pairs is globally fine-bucket-contiguous.
// ---------------------------------------------------------------------------
__global__ __launch_bounds__(512) void binB_kernel(
    const uint* __restrict__ stagingC, const int* __restrict__ gcurC,
    int* __restrict__ gcurF, uint* __restrict__ pairs)
{
    __shared__ uint stg[CHUNKB];    // 16 KB
    __shared__ int h32[BNODES];
    __shared__ int lcur[BNODES];
    __shared__ int wb[BNODES];

    int c = blockIdx.x / KMAX;
    int k = blockIdx.x % KMAX;
    int tid = threadIdx.x;

    int size = gcurC[c];
    if (size > CAPC) size = CAPC;
    int s0 = k * CHUNKB;
    if (s0 >= size) return;               // uniform exit before any barrier
    int cnt = size - s0; if (cnt > CHUNKB) cnt = CHUNKB;
    const uint* sp = stagingC + (size_t)c * CAPC + s0;

    if (tid < BNODES) h32[tid] = 0;
    __syncthreads();

    uint mypk[CHUNKB / 512];
#pragma unroll
    for (int q = 0; q < CHUNKB / 512; ++q) {
        int i = q * 512 + tid;
        if (i < cnt) {
            uint pk = sp[i];
            mypk[q] = pk;
            atomicAdd(&h32[(pk >> 21) & 31], 1);
        }
    }
    __syncthreads();
    if (tid < 64) {
        int v = (tid < BNODES) ? h32[tid] : 0;
        int s = v;
#pragma unroll
        for (int off = 1; off < BNODES; off <<= 1) {
            int u = __shfl_up(s, off);
            if (tid >= off) s += u;
        }
        if (tid < BNODES) {
            int excl = s - v;
            lcur[tid] = excl;
            int gp = 0;
            if (v > 0) gp = atomicAdd(&gcurF[c * BNODES + tid], v);
            wb[tid] = gp - excl;
        }
    }
    __syncthreads();
#pragma unroll
    for (int q = 0; q < CHUNKB / 512; ++q) {
        int i = q * 512 + tid;
        if (i < cnt) {
            uint pk = mypk[q];
            int p = atomicAdd(&lcur[(pk >> 21) & 31], 1);
            stg[p] = pk;
        }
    }
    __syncthreads();
#pragma unroll
    for (int q = 0; q < CHUNKB / 512; ++q) {
        int i = q * 512 + tid;
        if (i < cnt) {
            uint pk = stg[i];
            int f = (int)((pk >> 21) & 31);
            uint out = (pk & 0xFFFFu) | (((pk >> 16) & 31u) << 27);
            pairs[wb[f] + i] = out;
        }
    }
}

// ---------------------------------------------------------------------------
// K3: fused aggregate + MFMA GEMM. Block = 1 fine bucket (32 nodes), 256 thr.
// Bucket edges contiguous in pairs. Gather: each wave processes 4 nodes
// simultaneously, 8-deep, wave-uniform masked -> 32 outstanding loads, no
// per-node drain bubbles. MFMA epilogue unchanged.
// ---------------------------------------------------------------------------
__global__ __launch_bounds__(256, 6) void agg_gemm_kernel(
    const ushort* __restrict__ xbf, const uint* __restrict__ pairs,
    const int* __restrict__ gbase,
    const ushort* __restrict__ w1, const ushort* __restrict__ w2,
    const float* __restrict__ bias, float* __restrict__ out, int n_nodes)
{
    __shared__ uint sorted[TILE];               // 8 KB (byte offsets, src<<8)
    __shared__ uint abuf[BNODES * ASTRIDE];     // 8.7 KB
    __shared__ int hcnt[BNODES];
    __shared__ int hoff[BNODES + 1];
    __shared__ int hcur[BNODES];

    int blk   = blockIdx.x;      // == bucket index
    int node0 = blk * BNODES;
    int wave  = threadIdx.x >> 6;
    int lane  = threadIdx.x & 63;

    int start = gbase[blk];
    int end   = gbase[blk + 1];

    const char* xu = (const char*)xbf;
    uint lane4 = (uint)lane << 2;

    float2 acc[8];
#pragma unroll
    for (int i = 0; i < 8; ++i) acc[i] = make_float2(0.f, 0.f);

    for (int t0 = start; t0 < end; t0 += TILE) {
        int cnt = end - t0; if (cnt > TILE) cnt = TILE;

        if (threadIdx.x < BNODES) hcnt[threadIdx.x] = 0;
        __syncthreads();

        // pass A: coalesced read into registers + node histogram
        uint pk_[8];
#pragma unroll
        for (int k = 0; k < 8; ++k) {
            int i = threadIdx.x + k * 256;
            if (i < cnt) {
                uint pk = pairs[t0 + i];
                pk_[k] = pk;
                atomicAdd(&hcnt[pk >> 27], 1);
            }
        }
        __syncthreads();

        // 32-entry exclusive scan by wave 0 via shfl
        if (threadIdx.x < 64) {
            int v = (lane < BNODES) ? hcnt[lane] : 0;
#pragma unroll
            for (int off = 1; off < BNODES; off <<= 1) {
                int u = __shfl_up(v, off);
                if (lane >= off) v += u;
            }
            if (lane < BNODES) {
                hoff[lane + 1] = v;
                hcur[lane] = v - hcnt[lane];
            }
            if (lane == 0) hoff[0] = 0;
        }
        __syncthreads();

        // pass B: scatter pre-scaled row byte-offsets, node-sorted
#pragma unroll
        for (int k = 0; k < 8; ++k) {
            int i = threadIdx.x + k * 256;
            if (i < cnt) {
                uint pk = pk_[k];
                int p = atomicAdd(&hcur[pk >> 27], 1);
                sorted[p] = (pk & SRCMASK) << 8;   // byte offset of 256B row
            }
        }
        __syncthreads();

        // masked 4-segment x 8-deep gather (wave-uniform masks)
        int hv[9];
#pragma unroll
        for (int q = 0; q <= 8; ++q) hv[q] = hoff[wave * 8 + q];
        int safe = hv[0];          // valid (< cnt) whenever any mask is true
#pragma unroll
        for (int g = 0; g < 2; ++g) {
            int j0 = hv[g * 4 + 0], e0 = hv[g * 4 + 1];
            int j1 = e0,            e1 = hv[g * 4 + 2];
            int j2 = e1,            e2 = hv[g * 4 + 3];
            int j3 = e2,            e3 = hv[g * 4 + 4];
            int rem = e0 - j0;
            rem = max(rem, e1 - j1);
            rem = max(rem, e2 - j2);
            rem = max(rem, e3 - j3);
            float2 a0 = acc[g * 4 + 0], a1 = acc[g * 4 + 1];
            float2 a2 = acc[g * 4 + 2], a3 = acc[g * 4 + 3];
            while (rem > 0) {
                uint u0[8], u1[8], u2[8], u3[8];
#pragma unroll
                for (int k = 0; k < 8; ++k) {
                    int i0 = (j0 + k < e0) ? j0 + k : safe;
                    int i1 = (j1 + k < e1) ? j1 + k : safe;
                    int i2 = (j2 + k < e2) ? j2 + k : safe;
                    int i3 = (j3 + k < e3) ? j3 + k : safe;
                    u0[k] = *(const uint*)(xu + (size_t)(sorted[i0] + lane4));
                    u1[k] = *(const uint*)(xu + (size_t)(sorted[i1] + lane4));
                    u2[k] = *(const uint*)(xu + (size_t)(sorted[i2] + lane4));
                    u3[k] = *(const uint*)(xu + (size_t)(sorted[i3] + lane4));
                }
#pragma unroll
                for (int k = 0; k < 8; ++k) {
                    uint v0 = (j0 + k < e0) ? u0[k] : 0u;
                    uint v1 = (j1 + k < e1) ? u1[k] : 0u;
                    uint v2 = (j2 + k < e2) ? u2[k] : 0u;
                    uint v3 = (j3 + k < e3) ? u3[k] : 0u;
                    a0.x += __uint_as_float(v0 << 16);
                    a0.y += __uint_as_float(v0 & 0xffff0000u);
                    a1.x += __uint_as_float(v1 << 16);
                    a1.y += __uint_as_float(v1 & 0xffff0000u);
                    a2.x += __uint_as_float(v2 << 16);
                    a2.y += __uint_as_float(v2 & 0xffff0000u);
                    a3.x += __uint_as_float(v3 << 16);
                    a3.y += __uint_as_float(v3 & 0xffff0000u);
                }
                j0 += 8; j1 += 8; j2 += 8; j3 += 8;
                rem -= 8;
            }
            acc[g * 4 + 0] = a0; acc[g * 4 + 1] = a1;
            acc[g * 4 + 2] = a2; acc[g * 4 + 3] = a3;
        }
        __syncthreads();   // protect sorted/hist before next tile
    }

    // stage aggregated rows as bf16 into LDS (row stride 68 uints)
#pragma unroll
    for (int i = 0; i < 8; ++i) {
        int nl = wave * 8 + i;
        abuf[nl * ASTRIDE + lane] =
            (uint)f2bf(acc[i].x) | ((uint)f2bf(acc[i].y) << 16);
    }
    __syncthreads();

    // ---- MFMA phase: 2 waves per 16-row group; each does 4 of 8 o-tiles ----
    int quad = lane >> 4;
    int m    = lane & 15;
    int rg   = wave >> 1;          // row group 0..1
    int half = wave & 1;           // which 4 o-tiles
    int rowL = rg * 16 + m;
    int rowG = node0 + rowL;
    int rowC = (rowG < n_nodes) ? rowG : (n_nodes - 1);   // clamp loads

    short8 xa[4], aa[4];
#pragma unroll
    for (int ks = 0; ks < 4; ++ks) {
        xa[ks] = *reinterpret_cast<const short8*>(xbf + (size_t)rowC * DF + ks * 32 + quad * 8);
        aa[ks] = *reinterpret_cast<const short8*>(&abuf[rowL * ASTRIDE + ks * 16 + quad * 4]);
    }

    int nbase = node0 + rg * 16;
#pragma unroll
    for (int oi = 0; oi < 4; ++oi) {
        int ot = half * 4 + oi;
        int o = ot * 16 + m;
        floatx4 c = {0.f, 0.f, 0.f, 0.f};
#pragma unroll
        for (int ks = 0; ks < 4; ++ks) {
            short8 bf1 = *reinterpret_cast<const short8*>(w1 + (size_t)o * DF + ks * 32 + quad * 8);
            short8 bf2 = *reinterpret_cast<const short8*>(w2 + (size_t)o * DF + ks * 32 + quad * 8);
            c = __builtin_amdgcn_mfma_f32_16x16x32_bf16(xa[ks], bf1, c, 0, 0, 0);
            c = __builtin_amdgcn_mfma_f32_16x16x32_bf16(aa[ks], bf2, c, 0, 0, 0);
        }
        float bv = bias[o];
#pragma unroll
        for (int r = 0; r < 4; ++r) {
            int row = nbase + quad * 4 + r;
            if (row < n_nodes) out[(size_t)row * DF + o] = c[r] + bv;
        }
    }
}

extern "C" void kernel_launch(void* const* d_in, const int* in_sizes, int n_in,
                              void* d_out, int out_size, void* d_ws, size_t ws_size,
                              hipStream_t stream) {
    const float* x  = (const float*)d_in[0];
    const float* W1 = (const float*)d_in[1];
    const float* b1 = (const float*)d_in[2];
    const float* W2 = (const float*)d_in[3];
    const float* b2 = (const float*)d_in[4];
    const int* esrc = (const int*)d_in[5];
    const int* edst = (const int*)d_in[6];
    float* out = (float*)d_out;

    int n_nodes = in_sizes[0] / DF;
    int n_edges = in_sizes[5];

    int nb = (n_nodes + BNODES - 1) >> BSH;       // fine buckets (1563)
    int EB = (n_edges + PCHUNK - 1) / PCHUNK;     // edge blocks (196)
    int WB = (DF * DF + 511) / 512;               // weight convert blocks (32)

    char* ws = (char*)d_ws;
    ushort* xbf     = (ushort*)ws;               ws += (size_t)n_nodes * DF * 2;
    ushort* w1bf    = (ushort*)ws;               ws += (size_t)DF * DF * 2;
    ushort* w2bf    = (ushort*)ws;               ws += (size_t)DF * DF * 2;
    float*  bias    = (float*)ws;                ws += (size_t)DF * 4;
    int*    ghist   = (int*)ws;                  ws += (size_t)(nb + 1 + NC_) * 4;
    int*    done    = ghist + nb;
    int*    gcurC   = done + 1;
    int*    gbase   = (int*)ws;                  ws += (size_t)(nb + 1) * 4;
    int*    gcurF   = (int*)ws;                  ws += (size_t)nb * 4;
    uint*   stagingC= (uint*)ws;                 ws += (size_t)NC_ * CAPC * 4;
    uint*   pairs   = (uint*)ws;

    // zero [ghist | done | gcurC] each replay
    hipMemsetAsync(ghist, 0, (size_t)(nb + 1 + NC_) * sizeof(int), stream);

    int n4 = n_nodes * DF / 4;
    int XB = (n4 + 511) / 512;
    prep_kernel<<<EB + WB + XB, 512, 0, stream>>>(
        x, xbf, n4, W1, W2, b1, b2, w1bf, w2bf, bias,
        esrc, edst, ghist, done, gcurC, stagingC, gbase, gcurF,
        n_edges, EB, WB, nb);

    binB_kernel<<<NC_ * KMAX, 512, 0, stream>>>(stagingC, gcurC, gcurF, pairs);

    agg_gemm_kernel<<<nb, 256, 0, stream>>>(
        xbf, pairs, gbase, w1bf, w2bf, bias, out, n_nodes);
}

// Round 3
// 202.110 us; speedup vs baseline: 1.0455x; 1.0455x over previous
//
#include <hip/hip_runtime.h>
#include <hip/hip_bf16.h>

#define DF 128
#define BSH 4                 // bucket = dst >> 4  (16 nodes / bucket)
#define BNODES 16
#define NBMAX 4096            // max buckets (50000/16 = 3125)
#define CHUNK 8192            // edges per hist/bin block
#define BMAX 128              // max edge chunks (98 here; scan assumes <=128)
#define TILE 1024             // edges per aggregation LDS tile (bucket ~256)
#define ASTRIDE 68            // uints per abuf row (64 data + 4 pad)
#define SRCMASK 0x07ffffffu   // src in low 27 bits, dstLocal in bits 27..30

typedef __attribute__((ext_vector_type(8))) short short8;
typedef __attribute__((ext_vector_type(4))) float floatx4;

__device__ __forceinline__ ushort f2bf(float f) {
    __hip_bfloat16 h = __float2bfloat16(f);   // RNE
    return *reinterpret_cast<ushort*>(&h);
}

// ---------------------------------------------------------------------------
// K1: [0,B_) hist blocks | [B_,B_+64) weight convert (+ zero scan-done) |
// rest x convert.  histG layout: [block][bucket] (block-major -> flat scan
// gives each bin block a contiguous output region).  No global atomics.
// ---------------------------------------------------------------------------
__global__ __launch_bounds__(256) void prep_kernel(
    const float* __restrict__ x, ushort* __restrict__ xbf, int n4,
    const float* __restrict__ W1, const float* __restrict__ W2,
    const float* __restrict__ b1, const float* __restrict__ b2,
    ushort* __restrict__ w1bf, ushort* __restrict__ w2bf, float* __restrict__ bias,
    const int* __restrict__ dst, int* __restrict__ histG, int* __restrict__ sdone,
    int n_edges, int B_, int nb)
{
    __shared__ int h[NBMAX];
    int bid = blockIdx.x;
    if (bid < B_) {
        for (int j = threadIdx.x; j < nb; j += 256) h[j] = 0;
        __syncthreads();
        int base = bid * CHUNK;
#pragma unroll 4
        for (int i = 0; i < CHUNK / 256; ++i) {
            int e = base + i * 256 + threadIdx.x;
            if (e < n_edges) atomicAdd(&h[dst[e] >> BSH], 1);
        }
        __syncthreads();
        for (int j = threadIdx.x; j < nb; j += 256)
            histG[bid * nb + j] = h[j];
    } else if (bid < B_ + 64) {
        int i = (bid - B_) * 256 + threadIdx.x;
        if (i < DF * DF) {
            w1bf[i] = f2bf(W1[i]);
            w2bf[i] = f2bf(W2[i]);
        }
        if (i < DF) bias[i] = b1[i] + b2[i];
        if (bid == B_ && threadIdx.x == 0) *sdone = 0;
    } else {
        int i = (bid - B_ - 64) * 256 + threadIdx.x;
        if (i < n4) {
            float4 v = reinterpret_cast<const float4*>(x)[i];
            ushort4 o;
            o.x = f2bf(v.x); o.y = f2bf(v.y); o.z = f2bf(v.z); o.w = f2bf(v.w);
            reinterpret_cast<ushort4*>(xbf)[i] = o;
        }
    }
}

// ---------------------------------------------------------------------------
// K2: hierarchical exclusive scan; block-total scan fused in via done-counter
// (last block rewrites bsum[] to exclusive block bases with one wave).
// final_offs(idx) = histS[idx] + bsum[idx>>10].
// ---------------------------------------------------------------------------
__global__ __launch_bounds__(256) void scan_kernel(
    const int* __restrict__ cnt, int* __restrict__ offs,
    int* __restrict__ bsum, int* __restrict__ sdone, int n, int nb2)
{
    __shared__ int sd[256];
    __shared__ int isLast;
    int t = threadIdx.x;
    int base = blockIdx.x * 1024 + t * 4;

    int4 v = make_int4(0, 0, 0, 0);
    if (base + 3 < n) {
        v = *reinterpret_cast<const int4*>(cnt + base);
    } else {
        if (base + 0 < n) v.x = cnt[base + 0];
        if (base + 1 < n) v.y = cnt[base + 1];
        if (base + 2 < n) v.z = cnt[base + 2];
        if (base + 3 < n) v.w = cnt[base + 3];
    }
    int s = v.x + v.y + v.z + v.w;
    sd[t] = s;
    __syncthreads();
    for (int off = 1; off < 256; off <<= 1) {
        int u = (t >= off) ? sd[t - off] : 0;
        __syncthreads();
        sd[t] += u;
        __syncthreads();
    }
    int incl = sd[t];
    int excl = incl - s;
    if (t == 255) bsum[blockIdx.x] = incl;

    int p0 = excl, p1 = p0 + v.x, p2 = p1 + v.y, p3 = p2 + v.z;
    if (base + 0 < n) offs[base + 0] = p0;
    if (base + 1 < n) offs[base + 1] = p1;
    if (base + 2 < n) offs[base + 2] = p2;
    if (base + 3 < n) offs[base + 3] = p3;

    // fused scan of bsum[0..nb2) by the last-finishing block (one wave)
    __threadfence();
    __syncthreads();
    if (t == 0) isLast = (atomicAdd(sdone, 1) == gridDim.x - 1);
    __syncthreads();
    if (isLast && t < 64) {
        int b0 = t * 8;
        int tv[8];
        int run = 0;
#pragma unroll
        for (int k = 0; k < 8; ++k) {
            int idx = b0 + k;
            int u = (idx < nb2)
                ? __hip_atomic_load(&bsum[idx], __ATOMIC_RELAXED,
                                    __HIP_MEMORY_SCOPE_AGENT)
                : 0;
            tv[k] = u; run += u;
        }
        int laneTot = run;
        int sI = laneTot;
#pragma unroll
        for (int off = 1; off < 64; off <<= 1) {
            int u = __shfl_up(sI, off);
            if (t >= off) sI += u;
        }
        int laneExcl = sI - laneTot;
        int acc = laneExcl;
#pragma unroll
        for (int k = 0; k < 8; ++k) {
            int idx = b0 + k;
            if (idx < nb2) bsum[idx] = acc;
            acc += tv[k];
        }
    }
}

// ---------------------------------------------------------------------------
// K3: bin. Sort this block's CHUNK edges by bucket into LDS, then write its
// OWN CONTIGUOUS region [blk*CHUNK, blk*CHUNK+cnt) with coalesced stores.
// pairs[p] = src | dstLocal<<27.
// ---------------------------------------------------------------------------
__global__ __launch_bounds__(1024) void bin_kernel(
    const int* __restrict__ src, const int* __restrict__ dst,
    const int* __restrict__ histS, const int* __restrict__ bsum,
    uint* __restrict__ pairs, int n_edges, int B_, int nb)
{
    __shared__ int  cur[NBMAX];     // 16 KB global cursors
    __shared__ uint stage[CHUNK];   // 32 KB
    int blk = blockIdx.x;
    for (int j = threadIdx.x; j < nb; j += 1024) {
        int idx = blk * nb + j;
        cur[j] = histS[idx] + bsum[idx >> 10];
    }
    __syncthreads();
    int base = blk * CHUNK;
    int cnt = n_edges - base; if (cnt > CHUNK) cnt = CHUNK;
    for (int i = threadIdx.x; i < cnt; i += 1024) {
        int e = base + i;
        int d = dst[e];
        int j = d >> BSH;
        int p = atomicAdd(&cur[j], 1);
        stage[p - base] = (uint)src[e] | ((uint)(d & (BNODES - 1)) << 27);
    }
    __syncthreads();
    for (int i = threadIdx.x; i < cnt; i += 1024)
        pairs[base + i] = stage[i];
}

// ---------------------------------------------------------------------------
// K4: fused aggregate + MFMA GEMM. Block = 16 nodes = 1 bucket, 256 threads,
// 3125 blocks (2 generations/CU at 6 blocks resident -> refill smooths tail).
// Wave owns 4 nodes (~16 edges each = one 16-deep batch). Small LDS (9.5 KB).
// ---------------------------------------------------------------------------
__global__ __launch_bounds__(256, 6) void agg_gemm_kernel(
    const ushort* __restrict__ xbf, const uint* __restrict__ pairs,
    const int* __restrict__ histS, const int* __restrict__ bsum,
    const ushort* __restrict__ w1, const ushort* __restrict__ w2,
    const float* __restrict__ bias, float* __restrict__ out,
    int n_nodes, int n_edges, int B_, int nb, int flat)
{
    __shared__ uint sorted[TILE];               // 4 KB (byte offsets, src<<8)
    __shared__ uint abuf[BNODES * ASTRIDE];     // 4.35 KB
    __shared__ int  rstart[BMAX];
    __shared__ int  rexcl[BMAX + 1];
    __shared__ int hcnt[BNODES];
    __shared__ int hoff[BNODES + 1];
    __shared__ int hcur[BNODES];

    int blk  = blockIdx.x;      // == bucket index
    int node0 = blk * BNODES;
    int wave = threadIdx.x >> 6;
    int lane = threadIdx.x & 63;

    auto loadOffs = [&](int idx) -> int {
        if (idx >= flat) return n_edges;
        return histS[idx] + bsum[idx >> 10];
    };

    // runs: block j's cell for this bucket = [offs(j*nb+blk), offs(j*nb+blk+1))
    if (threadIdx.x < B_) {
        int idx = threadIdx.x * nb + blk;
        int s = loadOffs(idx);
        rstart[threadIdx.x] = s;
        rexcl[threadIdx.x]  = loadOffs(idx + 1) - s;   // count (temp)
    }
    __syncthreads();
    if (threadIdx.x < 64) {                            // wave 0: scan <=128 counts
        int c0 = (lane < B_) ? rexcl[lane] : 0;
        int c1 = (64 + lane < B_) ? rexcl[64 + lane] : 0;
        int s0 = c0, s1 = c1;
#pragma unroll
        for (int off = 1; off < 64; off <<= 1) {
            int u0 = __shfl_up(s0, off);
            int u1 = __shfl_up(s1, off);
            if (lane >= off) { s0 += u0; s1 += u1; }
        }
        int t0 = __shfl(s0, 63);
        int t1 = __shfl(s1, 63);
        if (lane < B_) rexcl[lane] = s0 - c0;
        if (64 + lane < B_) rexcl[64 + lane] = t0 + s1 - c1;
        if (lane == 0) rexcl[B_] = t0 + t1;            // total
    }
    __syncthreads();
    int total = rexcl[B_];

    const char* xu = (const char*)xbf;
    uint lane4 = (uint)lane << 2;

    float2 acc[4];
#pragma unroll
    for (int i = 0; i < 4; ++i) acc[i] = make_float2(0.f, 0.f);

    for (int t0 = 0; t0 < total; t0 += TILE) {
        int cnt = total - t0; if (cnt > TILE) cnt = TILE;

        if (threadIdx.x < BNODES) hcnt[threadIdx.x] = 0;
        __syncthreads();

        // pass A: binary-search run, read pair into registers, node-histogram
        uint pk_[TILE / 256];
#pragma unroll
        for (int k = 0; k < TILE / 256; ++k) {
            int i = threadIdx.x + k * 256;
            if (i < cnt) {
                int t = t0 + i;
                int lo = 0, hi = B_;
                while (lo + 1 < hi) {
                    int mid = (lo + hi) >> 1;
                    if (rexcl[mid] <= t) lo = mid; else hi = mid;
                }
                uint pk = pairs[rstart[lo] + (t - rexcl[lo])];
                pk_[k] = pk;
                atomicAdd(&hcnt[pk >> 27], 1);
            }
        }
        __syncthreads();

        // 16-entry exclusive scan by wave 0 via shfl
        if (threadIdx.x < 64) {
            int v = (lane < BNODES) ? hcnt[lane] : 0;
#pragma unroll
            for (int off = 1; off < BNODES; off <<= 1) {
                int u = __shfl_up(v, off);
                if (lane >= off) v += u;
            }
            if (lane < BNODES) {
                hoff[lane + 1] = v;
                hcur[lane] = v - hcnt[lane];
            }
            if (lane == 0) hoff[0] = 0;
        }
        __syncthreads();

        // pass B: scatter pre-scaled row byte-offsets, node-sorted
#pragma unroll
        for (int k = 0; k < TILE / 256; ++k) {
            int i = threadIdx.x + k * 256;
            if (i < cnt) {
                uint pk = pk_[k];
                int p = atomicAdd(&hcur[pk >> 27], 1);
                sorted[p] = (pk & SRCMASK) << 8;   // byte offset of 256B row
            }
        }
        __syncthreads();

        // wave owns nodes wave*4 .. wave*4+3; 16-deep independent gathers
#pragma unroll
        for (int i = 0; i < 4; ++i) {
            int nl = wave * 4 + i;
            int j0 = hoff[nl], j1 = hoff[nl + 1];
            float2 a = acc[i];
            int j = j0;
            for (; j + 15 < j1; j += 16) {
                uint u[16];
#pragma unroll
                for (int k = 0; k < 16; ++k)
                    u[k] = *(const uint*)(xu + (size_t)(sorted[j + k] + lane4));
#pragma unroll
                for (int k = 0; k < 16; ++k) {
                    a.x += __uint_as_float(u[k] << 16);
                    a.y += __uint_as_float(u[k] & 0xffff0000u);
                }
            }
            for (; j + 3 < j1; j += 4) {
                uint u0 = *(const uint*)(xu + (size_t)(sorted[j + 0] + lane4));
                uint u1 = *(const uint*)(xu + (size_t)(sorted[j + 1] + lane4));
                uint u2 = *(const uint*)(xu + (size_t)(sorted[j + 2] + lane4));
                uint u3 = *(const uint*)(xu + (size_t)(sorted[j + 3] + lane4));
                a.x += __uint_as_float(u0 << 16) + __uint_as_float(u1 << 16)
                     + __uint_as_float(u2 << 16) + __uint_as_float(u3 << 16);
                a.y += __uint_as_float(u0 & 0xffff0000u) + __uint_as_float(u1 & 0xffff0000u)
                     + __uint_as_float(u2 & 0xffff0000u) + __uint_as_float(u3 & 0xffff0000u);
            }
            for (; j < j1; ++j) {
                uint u = *(const uint*)(xu + (size_t)(sorted[j] + lane4));
                a.x += __uint_as_float(u << 16);
                a.y += __uint_as_float(u & 0xffff0000u);
            }
            acc[i] = a;
        }
        __syncthreads();   // protect sorted/hist before next tile
    }

    // stage aggregated rows as bf16 into LDS (row stride 68 uints)
#pragma unroll
    for (int i = 0; i < 4; ++i) {
        int nl = wave * 4 + i;
        abuf[nl * ASTRIDE + lane] =
            (uint)f2bf(acc[i].x) | ((uint)f2bf(acc[i].y) << 16);
    }
    __syncthreads();

    // ---- MFMA phase: 16 rows; wave w does o-tiles w*2, w*2+1 ----
    int quad = lane >> 4;
    int m    = lane & 15;
    int rowG = node0 + m;
    int rowC = (rowG < n_nodes) ? rowG : (n_nodes - 1);   // clamp loads

    short8 xa[4], aa[4];
#pragma unroll
    for (int ks = 0; ks < 4; ++ks) {
        xa[ks] = *reinterpret_cast<const short8*>(xbf + (size_t)rowC * DF + ks * 32 + quad * 8);
        aa[ks] = *reinterpret_cast<const short8*>(&abuf[m * ASTRIDE + ks * 16 + quad * 4]);
    }

#pragma unroll
    for (int oi = 0; oi < 2; ++oi) {
        int ot = wave * 2 + oi;
        int o = ot * 16 + m;
        floatx4 c = {0.f, 0.f, 0.f, 0.f};
#pragma unroll
        for (int ks = 0; ks < 4; ++ks) {
            short8 bf1 = *reinterpret_cast<const short8*>(w1 + (size_t)o * DF + ks * 32 + quad * 8);
            short8 bf2 = *reinterpret_cast<const short8*>(w2 + (size_t)o * DF + ks * 32 + quad * 8);
            c = __builtin_amdgcn_mfma_f32_16x16x32_bf16(xa[ks], bf1, c, 0, 0, 0);
            c = __builtin_amdgcn_mfma_f32_16x16x32_bf16(aa[ks], bf2, c, 0, 0, 0);
        }
        float bv = bias[o];
#pragma unroll
        for (int r = 0; r < 4; ++r) {
            int row = node0 + quad * 4 + r;
            if (row < n_nodes) out[(size_t)row * DF + o] = c[r] + bv;
        }
    }
}

extern "C" void kernel_launch(void* const* d_in, const int* in_sizes, int n_in,
                              void* d_out, int out_size, void* d_ws, size_t ws_size,
                              hipStream_t stream) {
    const float* x  = (const float*)d_in[0];
    const float* W1 = (const float*)d_in[1];
    const float* b1 = (const float*)d_in[2];
    const float* W2 = (const float*)d_in[3];
    const float* b2 = (const float*)d_in[4];
    const int* esrc = (const int*)d_in[5];
    const int* edst = (const int*)d_in[6];
    float* out = (float*)d_out;

    int n_nodes = in_sizes[0] / DF;
    int n_edges = in_sizes[5];

    int nb = (n_nodes + BNODES - 1) >> BSH;       // buckets (3125)
    int B_ = (n_edges + CHUNK - 1) / CHUNK;       // edge chunks (98, <= BMAX)
    int flat = nb * B_;                           // hist matrix size (~306k)

    char* ws = (char*)d_ws;
    ushort* xbf   = (ushort*)ws;                 ws += (size_t)n_nodes * DF * 2;
    ushort* w1bf  = (ushort*)ws;                 ws += (size_t)DF * DF * 2;
    ushort* w2bf  = (ushort*)ws;                 ws += (size_t)DF * DF * 2;
    float*  bias  = (float*)ws;                  ws += (size_t)DF * 4;
    int*    histG = (int*)ws;                    ws += (size_t)flat * 4;
    int*    histS = (int*)ws;                    ws += (size_t)(flat + 1) * 4;
    int*    bsum  = (int*)ws;                    ws += 512 * 4;
    int*    sdone = (int*)ws;                    ws += 4;
    uint*   pairs = (uint*)ws;

    int n4 = n_nodes * DF / 4;
    int prep_blocks = B_ + 64 + (n4 + 255) / 256;
    prep_kernel<<<prep_blocks, 256, 0, stream>>>(
        x, xbf, n4, W1, W2, b1, b2, w1bf, w2bf, bias,
        edst, histG, sdone, n_edges, B_, nb);

    int nb2 = (flat + 1023) / 1024;
    scan_kernel<<<nb2, 256, 0, stream>>>(histG, histS, bsum, sdone, flat, nb2);

    bin_kernel<<<B_, 1024, 0, stream>>>(esrc, edst, histS, bsum, pairs, n_edges, B_, nb);

    agg_gemm_kernel<<<nb, 256, 0, stream>>>(
        xbf, pairs, histS, bsum, w1bf, w2bf, bias, out,
        n_nodes, n_edges, B_, nb, flat);
}